// Round 9
// baseline (195.686 us; speedup 1.0000x reference)
//
#include <hip/hip_runtime.h>

#define S 256
#define L2E 1.44269504088896340736f   // log2(e)
#define LN2 0.69314718055994530942f

// Raw HW transcendentals: v_exp_f32 = 2^x, v_log_f32 = log2(x).
#define EXP2F(x) __builtin_amdgcn_exp2f(x)
#define LOG2F(x) __builtin_amdgcn_logf(x)

// Probability-domain soft-min DP. One wave per batch, thread t owns rows
// 4t..4t+3. Carry w = 2^(sigma - E) where E = D*log2(e):
//   softmin update:  w_new = g * (w_a + w_b + w_c),  g = 2^(-C*log2e)
// -> 1 transcendental per cell (at LOAD time, off the critical path) vs 4,
//    BIG == 0 exactly (additive identity), no per-cell log2.
// Block-floating renorm every 32 diagonals: wave-max -> exact 2^-e rescale,
// integer sigma accumulator (lossless): E = sigma - log2(w), so w *= 2^-e
// requires sigma -= e (Round-8 bug was sigma += e -> output ~ -D).
// Neighbor row 4t-1 via ONE shfl/step (pd2(k) == pd1(k-1)), issued at the
// END of the previous step so ds_bpermute latency hides under the step.

template <int I> __device__ __forceinline__ float comp(const float4& v) {
    if constexpr (I == 0) return v.x;
    else if constexpr (I == 1) return v.y;
    else if constexpr (I == 2) return v.z;
    else return v.w;
}

__device__ __forceinline__ float4 g4(const float4& v) {
    float4 r;
    r.x = EXP2F(v.x * -L2E); r.y = EXP2F(v.y * -L2E);
    r.z = EXP2F(v.z * -L2E); r.w = EXP2F(v.w * -L2E);
    return r;
}

template <int P>
__device__ __forceinline__ void stepf(
    int kk, int t, int t4, const float* __restrict__ Cb,
    int ro0, int ro1, int ro2, int ro3,
    float4& c0, float4& c1, float4& c2, float4& c3,
    float4& n0, float4& n1, float4& n2, float4& n3,
    float4& x0, float4& x1, float4& x2, float4& x3,
    float& w10, float& w11, float& w12, float& w13,
    float& w20, float& w21, float& w22, float& w23,
    float& pd1, float& pd2)
{
    const int jp = kk - t4 - P;            // designated row P's column (multiple of 4)
    const int roP = (P == 0) ? ro0 : (P == 1) ? ro1 : (P == 2) ? ro2 : ro3;

    float4& cP = (P == 0) ? c0 : (P == 1) ? c1 : (P == 2) ? c2 : c3;
    float4& nP = (P == 0) ? n0 : (P == 1) ? n1 : (P == 2) ? n2 : n3;
    float4& xP = (P == 0) ? x0 : (P == 1) ? x1 : (P == 2) ? x2 : x3;
    if (jp > 0 && jp < S) { cP = nP; nP = xP; }
    if (jp > 0 && jp <= S - 12) {
        // loads columns jp+8..jp+11 of row 4t+P (ro includes the +8)
        xP = g4(*(const float4*)(Cb + roP + jp));
    }

    // per-row g, masked to 0 for j >= S (junk region must stay w == 0;
    // j < 0 cells are 0 automatically since all their inputs are 0)
    const int j0 = kk - t4;
    float g0 = (j0     <= S - 1) ? comp<(P    ) & 3>(c0) : 0.0f;
    float g1 = (j0 - 1 <= S - 1) ? comp<(P + 3) & 3>(c1) : 0.0f;
    float g2 = (j0 - 2 <= S - 1) ? comp<(P + 2) & 3>(c2) : 0.0f;
    float g3 = (j0 - 3 <= S - 1) ? comp<(P + 1) & 3>(c3) : 0.0f;

    float e0 = g0 * (w10 + pd1 + pd2);     // a=own prev, b=up prev, c=up prev2
    float e1 = g1 * (w11 + w10 + w20);
    float e2 = g2 * (w12 + w11 + w21);
    float e3 = g3 * (w13 + w12 + w22);

    w20 = w10; w21 = w11; w22 = w12; w23 = w13;
    w10 = e0;  w11 = e1;  w12 = e2;  w13 = e3;

    // neighbor pipeline for NEXT step: pd2(k+1) = pd1(k); pd1(k+1) = shfl(e3)
    float nx = __shfl_up(e3, 1);
    pd2 = pd1;
    pd1 = (t == 0) ? 0.0f : nx;
}

__global__ __launch_bounds__(64, 1) void dp_softmin_wave(const float* __restrict__ C,
                                                         float* __restrict__ out) {
    const int b = blockIdx.x;
    const int t = threadIdx.x;
    const float* Cb = C + ((size_t)b << 16);
    const int t4 = 4 * t;

    const int ro0 = ((t4 + 0) << 8) + 8;
    const int ro1 = ((t4 + 1) << 8) + 8;
    const int ro2 = ((t4 + 2) << 8) + 8;
    const int ro3 = ((t4 + 3) << 8) + 8;

    const float* R0 = Cb + ((size_t)(t4 + 0) << 8);
    const float* R1 = Cb + ((size_t)(t4 + 1) << 8);
    const float* R2 = Cb + ((size_t)(t4 + 2) << 8);
    const float* R3 = Cb + ((size_t)(t4 + 3) << 8);

    float4 c0 = g4(*(const float4*)(R0)),     c1 = g4(*(const float4*)(R1)),
           c2 = g4(*(const float4*)(R2)),     c3 = g4(*(const float4*)(R3));
    float4 n0 = g4(*(const float4*)(R0 + 4)), n1 = g4(*(const float4*)(R1 + 4)),
           n2 = g4(*(const float4*)(R2 + 4)), n3 = g4(*(const float4*)(R3 + 4));
    float4 x0 = g4(*(const float4*)(R0 + 8)), x1 = g4(*(const float4*)(R1 + 8)),
           x2 = g4(*(const float4*)(R2 + 8)), x3 = g4(*(const float4*)(R3 + 8));

    float w10 = 0.0f, w11 = 0.0f, w12 = 0.0f, w13 = 0.0f;
    float w20 = 0.0f, w21 = 0.0f, w22 = 0.0f, w23 = 0.0f;
    float pd1 = 0.0f, pd2 = 0.0f;
    int sig = 0;

    if (t == 0) w10 = c0.x;                // seed: w(0,0) = g(0,0), sigma = 0

#define ARGS t, t4, Cb, ro0, ro1, ro2, ro3, c0,c1,c2,c3, n0,n1,n2,n3, x0,x1,x2,x3, \
             w10,w11,w12,w13, w20,w21,w22,w23, pd1,pd2

    stepf<1>(1, ARGS);
    stepf<2>(2, ARGS);
    stepf<3>(3, ARGS);
    for (int kb = 4; kb <= 504; kb += 4) {
        stepf<0>(kb + 0, ARGS);
        stepf<1>(kb + 1, ARGS);
        stepf<2>(kb + 2, ARGS);
        stepf<3>(kb + 3, ARGS);
        if ((kb & 31) == 4) {
            // block-floating renorm: exact power-of-2, integer sigma.
            // E = sig - log2(w): w *= 2^-e  ==>  sig -= e  (keeps E invariant)
            float M = fmaxf(fmaxf(fmaxf(w10, w11), fmaxf(w12, w13)),
                            fmaxf(fmaxf(w20, w21), fmaxf(w22, w23)));
            #pragma unroll
            for (int m = 1; m < 64; m <<= 1) M = fmaxf(M, __shfl_xor(M, m));
            int e = ((__float_as_int(M) >> 23) & 255) - 127;
            float f = __int_as_float((127 - e) << 23);
            w10 *= f; w11 *= f; w12 *= f; w13 *= f;
            w20 *= f; w21 *= f; w22 *= f; w23 *= f;
            pd1 *= f; pd2 *= f;
            sig -= e;
        }
    }
    stepf<0>(508, ARGS);
    stepf<1>(509, ARGS);
    stepf<2>(510, ARGS);
#undef ARGS

    // corner cell (255,255): lane 63, w13. D = (sigma - log2 w) * ln2... with
    // E = sig - log2(w13):  D = E * ln2
    if (t == 63) out[b] = ((float)sig - LOG2F(w13)) * LN2;
}

extern "C" void kernel_launch(void* const* d_in, const int* in_sizes, int n_in,
                              void* d_out, int out_size, void* d_ws, size_t ws_size,
                              hipStream_t stream) {
    const float* C = (const float*)d_in[0];
    float* out = (float*)d_out;
    dp_softmin_wave<<<512, 64, 0, stream>>>(C, out);
}

// Round 10
// 184.519 us; speedup vs baseline: 1.0605x; 1.0605x over previous
//
#include <hip/hip_runtime.h>

#define S 256
#define L2E 1.44269504088896340736f   // log2(e)
#define LN2 0.69314718055994530942f

// Raw HW transcendentals: v_exp_f32 = 2^x, v_log_f32 = log2(x).
#define EXP2F(x) __builtin_amdgcn_exp2f(x)
#define LOG2F(x) __builtin_amdgcn_logf(x)

// Probability-domain soft-min DP. One wave per batch, thread t owns rows
// 4t..4t+3. Carry w = 2^(sigma - E), E = D*log2(e):
//   w_new = g * (w_a + w_b + w_c),  g = 2^(-C*log2e);  BIG == 0 exactly.
// Pipeline (the round-5/6 structure that measured best):
//   xP : RAW float4 just loaded          (written by global_load)
//   nP : g-converted, = g4(xP) at rotation (load +4 steps -> vmcnt slack)
//   cP : g-converted, consumed by cells    (load +8 steps)
// No transcendental touches data younger than 4 steps -> no exposed vmcnt
// stall (round-9 regression was g4 directly on the loaded value).
// One shfl/step (pd2(k)=pd1(k-1)), issued at end of step k, used at start
// of k+1 -> latency hidden by the step's independent work.
// Block-floating renorm every 32 diagonals (exact 2^-e, sigma -= e).

template <int I> __device__ __forceinline__ float comp(const float4& v) {
    if constexpr (I == 0) return v.x;
    else if constexpr (I == 1) return v.y;
    else if constexpr (I == 2) return v.z;
    else return v.w;
}

__device__ __forceinline__ float4 g4(const float4& v) {
    float4 r;
    r.x = EXP2F(v.x * -L2E); r.y = EXP2F(v.y * -L2E);
    r.z = EXP2F(v.z * -L2E); r.w = EXP2F(v.w * -L2E);
    return r;
}

template <int P>
__device__ __forceinline__ void stepf(
    int kk, int t, int t4, const float* __restrict__ Cb,
    int ro0, int ro1, int ro2, int ro3,
    float4& c0, float4& c1, float4& c2, float4& c3,
    float4& n0, float4& n1, float4& n2, float4& n3,
    float4& x0, float4& x1, float4& x2, float4& x3,
    float& w10, float& w11, float& w12, float& w13,
    float& w20, float& w21, float& w22, float& w23,
    float& pd1, float& pd2)
{
    const int jp = kk - t4 - P;            // designated row P's column (multiple of 4)
    const int roP = (P == 0) ? ro0 : (P == 1) ? ro1 : (P == 2) ? ro2 : ro3;

    float4& cP = (P == 0) ? c0 : (P == 1) ? c1 : (P == 2) ? c2 : c3;
    float4& nP = (P == 0) ? n0 : (P == 1) ? n1 : (P == 2) ? n2 : n3;
    float4& xP = (P == 0) ? x0 : (P == 1) ? x1 : (P == 2) ? x2 : x3;
    if (jp > 0 && jp < S) {
        cP = nP;
        nP = g4(xP);                       // xP loaded 4 steps ago: slack covers vmem
        if (jp <= S - 12)                  // loads columns jp+8..jp+11 (ro has the +8)
            xP = *(const float4*)(Cb + roP + jp);
    }

    // per-row g from the (old) converted quads; mask j >= S junk region to 0
    const int j0 = kk - t4;
    float g0 = (j0     < S) ? comp<(P    ) & 3>(c0) : 0.0f;
    float g1 = (j0 - 1 < S) ? comp<(P + 3) & 3>(c1) : 0.0f;
    float g2 = (j0 - 2 < S) ? comp<(P + 2) & 3>(c2) : 0.0f;
    float g3 = (j0 - 3 < S) ? comp<(P + 1) & 3>(c3) : 0.0f;

    float e0 = g0 * (w10 + pd1 + pd2);     // a=own prev, b=up prev, c=up prev2
    float e1 = g1 * (w11 + w10 + w20);
    float e2 = g2 * (w12 + w11 + w21);
    float e3 = g3 * (w13 + w12 + w22);

    w20 = w10; w21 = w11; w22 = w12; w23 = w13;
    w10 = e0;  w11 = e1;  w12 = e2;  w13 = e3;

    // neighbor pipeline for NEXT step: pd2(k+1) = pd1(k); pd1(k+1) = shfl(e3)
    float nx = __shfl_up(e3, 1);
    pd2 = pd1;
    pd1 = (t == 0) ? 0.0f : nx;
}

__global__ __launch_bounds__(64, 1) void dp_softmin_wave(const float* __restrict__ C,
                                                         float* __restrict__ out) {
    const int b = blockIdx.x;
    const int t = threadIdx.x;
    const float* Cb = C + ((size_t)b << 16);
    const int t4 = 4 * t;

    const int ro0 = ((t4 + 0) << 8) + 8;
    const int ro1 = ((t4 + 1) << 8) + 8;
    const int ro2 = ((t4 + 2) << 8) + 8;
    const int ro3 = ((t4 + 3) << 8) + 8;

    const float* R0 = Cb + ((size_t)(t4 + 0) << 8);
    const float* R1 = Cb + ((size_t)(t4 + 1) << 8);
    const float* R2 = Cb + ((size_t)(t4 + 2) << 8);
    const float* R3 = Cb + ((size_t)(t4 + 3) << 8);

    float4 c0 = g4(*(const float4*)(R0)),     c1 = g4(*(const float4*)(R1)),
           c2 = g4(*(const float4*)(R2)),     c3 = g4(*(const float4*)(R3));
    float4 n0 = g4(*(const float4*)(R0 + 4)), n1 = g4(*(const float4*)(R1 + 4)),
           n2 = g4(*(const float4*)(R2 + 4)), n3 = g4(*(const float4*)(R3 + 4));
    float4 x0 = *(const float4*)(R0 + 8),     x1 = *(const float4*)(R1 + 8),
           x2 = *(const float4*)(R2 + 8),     x3 = *(const float4*)(R3 + 8);   // RAW

    float w10 = 0.0f, w11 = 0.0f, w12 = 0.0f, w13 = 0.0f;
    float w20 = 0.0f, w21 = 0.0f, w22 = 0.0f, w23 = 0.0f;
    float pd1 = 0.0f, pd2 = 0.0f;
    int sig = 0;

    if (t == 0) w10 = c0.x;                // seed: w(0,0) = g(0,0), sigma = 0

#define ARGS t, t4, Cb, ro0, ro1, ro2, ro3, c0,c1,c2,c3, n0,n1,n2,n3, x0,x1,x2,x3, \
             w10,w11,w12,w13, w20,w21,w22,w23, pd1,pd2

    stepf<1>(1, ARGS);
    stepf<2>(2, ARGS);
    stepf<3>(3, ARGS);
#pragma clang loop unroll(disable)
    for (int kb = 4; kb <= 504; kb += 4) {
        stepf<0>(kb + 0, ARGS);
        stepf<1>(kb + 1, ARGS);
        stepf<2>(kb + 2, ARGS);
        stepf<3>(kb + 3, ARGS);
        if ((kb & 31) == 4) {
            // block-floating renorm: exact power-of-2, integer sigma.
            // E = sig - log2(w): w *= 2^-e  ==>  sig -= e  (keeps E invariant)
            float M = fmaxf(fmaxf(fmaxf(w10, w11), fmaxf(w12, w13)),
                            fmaxf(fmaxf(w20, w21), fmaxf(w22, w23)));
            #pragma unroll
            for (int m = 1; m < 64; m <<= 1) M = fmaxf(M, __shfl_xor(M, m));
            int e = ((__float_as_int(M) >> 23) & 255) - 127;
            float f = __int_as_float((127 - e) << 23);
            w10 *= f; w11 *= f; w12 *= f; w13 *= f;
            w20 *= f; w21 *= f; w22 *= f; w23 *= f;
            pd1 *= f; pd2 *= f;
            sig -= e;
        }
    }
    stepf<0>(508, ARGS);
    stepf<1>(509, ARGS);
    stepf<2>(510, ARGS);
#undef ARGS

    // corner cell (255,255): lane 63, E = sig - log2(w13), D = E * ln2
    if (t == 63) out[b] = ((float)sig - LOG2F(w13)) * LN2;
}

extern "C" void kernel_launch(void* const* d_in, const int* in_sizes, int n_in,
                              void* d_out, int out_size, void* d_ws, size_t ws_size,
                              hipStream_t stream) {
    const float* C = (const float*)d_in[0];
    float* out = (float*)d_out;
    dp_softmin_wave<<<512, 64, 0, stream>>>(C, out);
}

// Round 11
// 75.560 us; speedup vs baseline: 2.5898x; 2.4420x over previous
//
#include <hip/hip_runtime.h>

#define S 256
#define L2E 1.44269504088896340736f   // log2(e)
#define LN2 0.69314718055994530942f

// Raw HW transcendentals: v_exp_f32 = 2^x, v_log_f32 = log2(x).
#define EXP2F(x) __builtin_amdgcn_exp2f(x)
#define LOG2F(x) __builtin_amdgcn_logf(x)

// Probability-domain soft-min DP, FULLY BRANCHLESS body.
// One wave per batch, thread t owns rows 4t..4t+3 (row r = 4t+P).
// w = 2^(sigma - E), E = D*log2e;  w_new = g*(wa+wb+wc), g = 2^(-C*l2e).
// Per step kk (phase P = kk&3, slot parity SB = (kk>>2)&1), ALL lanes:
//   - ONE clamped unconditional load: col = clamp(kk+12-P-t4, 0, 252)
//   - rotation of row P's quad pipeline: cP=nP; nP=g4(slot); slot=ld
//     (ping-pong slots xa/xb -> a load is first read 8 steps after issue;
//      no divergent skip -> STATIC vmcnt counting -> pipelined loads)
//   - junk-zero at conversion: slot loaded 8 steps ago had col>252 (i.e.
//     colr_now>260) -> g=0, so the j>=S region stays exactly 0
//   - 4 cells e_r = g_r*(3-term sum), 1 shfl_up for the lane boundary
// Pre-start lanes reload quad 0 (harmless: their w's are all 0).
// Pipeline invariant: after rotation at kk, cP covers cols clamp(jp_r),
// jp_r = kk-t4-P (verified by hand for lane 0 start and lane 63 end).
// Renorm every 64 diagonals (growth <= 3^64 = 2^101 < 2^127): wave-max,
// exact 2^-e scaling, sigma -= e.

template <int I> __device__ __forceinline__ float comp(const float4& v) {
    if constexpr (I == 0) return v.x;
    else if constexpr (I == 1) return v.y;
    else if constexpr (I == 2) return v.z;
    else return v.w;
}

__device__ __forceinline__ float4 g4f(const float4& v) {
    float4 r;
    r.x = EXP2F(v.x * -L2E); r.y = EXP2F(v.y * -L2E);
    r.z = EXP2F(v.z * -L2E); r.w = EXP2F(v.w * -L2E);
    return r;
}

template <int P, int SB>
__device__ __forceinline__ void stepf(
    int kk, int t, int t4, const float* __restrict__ Cb,
    int rb0, int rb1, int rb2, int rb3,
    float4& c0, float4& c1, float4& c2, float4& c3,
    float4& n0, float4& n1, float4& n2, float4& n3,
    float4& xa0, float4& xa1, float4& xa2, float4& xa3,
    float4& xb0, float4& xb1, float4& xb2, float4& xb3,
    float& w10, float& w11, float& w12, float& w13,
    float& w20, float& w21, float& w22, float& w23,
    float& pd1, float& pd2)
{
    const int colr = kk + (12 - P) - t4;
    const int col  = colr < 0 ? 0 : (colr > 252 ? 252 : colr);
    const int rb   = (P == 0) ? rb0 : (P == 1) ? rb1 : (P == 2) ? rb2 : rb3;
    const float4 ld = *(const float4*)(Cb + rb + col);   // unconditional

    float4& cP = (P == 0) ? c0 : (P == 1) ? c1 : (P == 2) ? c2 : c3;
    float4& nP = (P == 0) ? n0 : (P == 1) ? n1 : (P == 2) ? n2 : n3;
    float4& sP = SB ? ((P == 0) ? xb0 : (P == 1) ? xb1 : (P == 2) ? xb2 : xb3)
                    : ((P == 0) ? xa0 : (P == 1) ? xa1 : (P == 2) ? xa2 : xa3);

    // convert the slot loaded 8 steps ago; zero it if it was past-the-end
    const bool junk = (colr > 260);
    float4 gq;
    gq.x = junk ? 0.0f : EXP2F(sP.x * -L2E);
    gq.y = junk ? 0.0f : EXP2F(sP.y * -L2E);
    gq.z = junk ? 0.0f : EXP2F(sP.z * -L2E);
    gq.w = junk ? 0.0f : EXP2F(sP.w * -L2E);
    cP = nP;
    nP = gq;
    sP = ld;

    const float g0 = comp<(P    ) & 3>(c0);
    const float g1 = comp<(P + 3) & 3>(c1);
    const float g2 = comp<(P + 2) & 3>(c2);
    const float g3 = comp<(P + 1) & 3>(c3);

    const float e0 = g0 * (w10 + pd1 + pd2);   // preds: (r-1,j)=pd1, (r,j-1)=w10, (r-1,j-1)=pd2
    const float e1 = g1 * (w11 + w10 + w20);
    const float e2 = g2 * (w12 + w11 + w21);
    const float e3 = g3 * (w13 + w12 + w22);

    w20 = w10; w21 = w11; w22 = w12; w23 = w13;
    w10 = e0;  w11 = e1;  w12 = e2;  w13 = e3;

    const float nx = __shfl_up(e3, 1);
    pd2 = pd1;
    pd1 = (t == 0) ? 0.0f : nx;
}

__global__ __launch_bounds__(64, 1) void dp_softmin_wave(const float* __restrict__ C,
                                                         float* __restrict__ out) {
    const int b = blockIdx.x;
    const int t = threadIdx.x;
    const float* Cb = C + ((size_t)b << 16);
    const int t4 = 4 * t;

    const int rb0 = (t4 + 0) << 8;
    const int rb1 = (t4 + 1) << 8;
    const int rb2 = (t4 + 2) << 8;
    const int rb3 = (t4 + 3) << 8;

    auto cl = [](int c) { return c < 0 ? 0 : (c > 252 ? 252 : c); };
    auto q  = [&](int rb, int col) { return *(const float4*)(Cb + rb + col); };

    // init = fixed point of the unconditional machine for kk <= 0:
    //   cP = g4(col_L(kkr-12)), nP = g4(col_L(kkr-8)),
    //   slots = raw col_L(kkr), col_L(kkr-4)  (kkr = last virtual rotation)
    float4 c0 = g4f(q(rb0, 0)), c1 = g4f(q(rb1, 0)),
           c2 = g4f(q(rb2, 0)), c3 = g4f(q(rb3, 0));
    float4 n0 = g4f(q(rb0, cl(4 - t4)));
    float4 n1 = c1, n2 = c2, n3 = c3;
    float4 xa0 = q(rb0, cl(12 - t4));
    float4 xa1 = q(rb1, cl(4 - t4));
    float4 xa2 = q(rb2, cl(4 - t4));
    float4 xa3 = q(rb3, cl(4 - t4));
    float4 xb0 = q(rb0, cl(8 - t4));
    float4 xb1 = q(rb1, cl(8 - t4));
    float4 xb2 = q(rb2, cl(8 - t4));
    float4 xb3 = q(rb3, cl(8 - t4));

    float w10 = 0.0f, w11 = 0.0f, w12 = 0.0f, w13 = 0.0f;
    float w20 = 0.0f, w21 = 0.0f, w22 = 0.0f, w23 = 0.0f;
    float pd1 = 0.0f, pd2 = 0.0f;
    int sig = 0;

    if (t == 0) w10 = c0.x;                // seed: w(0,0) = g(0,0)

#define ARGS t, t4, Cb, rb0, rb1, rb2, rb3, c0,c1,c2,c3, n0,n1,n2,n3, \
             xa0,xa1,xa2,xa3, xb0,xb1,xb2,xb3, \
             w10,w11,w12,w13, w20,w21,w22,w23, pd1,pd2

    // prologue kk = 1..7
    stepf<1,0>(1, ARGS);
    stepf<2,0>(2, ARGS);
    stepf<3,0>(3, ARGS);
    stepf<0,1>(4, ARGS);
    stepf<1,1>(5, ARGS);
    stepf<2,1>(6, ARGS);
    stepf<3,1>(7, ARGS);

#pragma clang loop unroll(disable)
    for (int kb = 8; kb <= 496; kb += 8) {
        if ((kb & 63) == 0) {
            // block-floating renorm: exact power-of-2, sigma -= e
            float M = fmaxf(fmaxf(fmaxf(w10, w11), fmaxf(w12, w13)),
                            fmaxf(fmaxf(w20, w21), fmaxf(w22, w23)));
            #pragma unroll
            for (int m = 1; m < 64; m <<= 1) M = fmaxf(M, __shfl_xor(M, m));
            int e = ((__float_as_int(M) >> 23) & 255) - 127;
            float f = __int_as_float((127 - e) << 23);
            w10 *= f; w11 *= f; w12 *= f; w13 *= f;
            w20 *= f; w21 *= f; w22 *= f; w23 *= f;
            pd1 *= f; pd2 *= f;
            sig -= e;
        }
        stepf<0,0>(kb + 0, ARGS);
        stepf<1,0>(kb + 1, ARGS);
        stepf<2,0>(kb + 2, ARGS);
        stepf<3,0>(kb + 3, ARGS);
        stepf<0,1>(kb + 4, ARGS);
        stepf<1,1>(kb + 5, ARGS);
        stepf<2,1>(kb + 6, ARGS);
        stepf<3,1>(kb + 7, ARGS);
    }

    // epilogue kk = 504..510
    stepf<0,0>(504, ARGS);
    stepf<1,0>(505, ARGS);
    stepf<2,0>(506, ARGS);
    stepf<3,0>(507, ARGS);
    stepf<0,1>(508, ARGS);
    stepf<1,1>(509, ARGS);
    stepf<2,1>(510, ARGS);
#undef ARGS

    // corner cell (255,255): lane 63, E = sig - log2(w13), D = E * ln2
    if (t == 63) out[b] = ((float)sig - LOG2F(w13)) * LN2;
}

extern "C" void kernel_launch(void* const* d_in, const int* in_sizes, int n_in,
                              void* d_out, int out_size, void* d_ws, size_t ws_size,
                              hipStream_t stream) {
    const float* C = (const float*)d_in[0];
    float* out = (float*)d_out;
    dp_softmin_wave<<<512, 64, 0, stream>>>(C, out);
}

// Round 12
// 68.498 us; speedup vs baseline: 2.8568x; 1.1031x over previous
//
#include <hip/hip_runtime.h>

#define S 256
#define L2E 1.44269504088896340736f   // log2(e)
#define LN2 0.69314718055994530942f

// Raw HW transcendentals: v_exp_f32 = 2^x, v_log_f32 = log2(x).
#define EXP2F(x) __builtin_amdgcn_exp2f(x)
#define LOG2F(x) __builtin_amdgcn_logf(x)

// Probability-domain soft-min DP, fully branchless body, 16-DEEP load pipe.
// One wave per batch, thread t owns rows 4t..4t+3 (row r = 4t+P).
// w = 2^(sigma - E), E = D*log2e;  w_new = g*(wa+wb+wc), g = 2^(-C*l2e).
// Per step kk (phase P = kk&3, slot bank SB = (kk>>2)&3), ALL lanes:
//   - ONE clamped unconditional load: colr = kk+20-P-t4, col = clamp(colr,0,252)
//     -> written to slot[P][SB]; that slot is next read 16 steps later.
//   - rotation of row P's pipeline: cP = nP; nP = g4(slot[P][SB]); slot = ld
//     (conversion reads the load issued 16 steps ago: ~16*step cycles of
//      vmcnt slack covers full HBM latency; static vmcnt counting since
//      there are no divergent skips)
//   - junk-zero at conversion: the slot's load had col clamped above
//     (colr_then = colr-16 > 252  <=>  colr > 268) -> g = 0, so the
//     j >= S junk region stays exactly 0
//   - 4 cells e_r = g_r*(3-term sum), 1 shfl_up for the lane boundary
// Pre-start lanes reload col 0 (harmless: their w inputs are all 0).
// Renorm every 64 diagonals (growth <= 3^64 = 2^101): wave-max, exact
// 2^-e scaling, sigma -= e  (E = sig - log2 w stays invariant).

template <int I> __device__ __forceinline__ float comp(const float4& v) {
    if constexpr (I == 0) return v.x;
    else if constexpr (I == 1) return v.y;
    else if constexpr (I == 2) return v.z;
    else return v.w;
}

__device__ __forceinline__ float4 g4f(const float4& v) {
    float4 r;
    r.x = EXP2F(v.x * -L2E); r.y = EXP2F(v.y * -L2E);
    r.z = EXP2F(v.z * -L2E); r.w = EXP2F(v.w * -L2E);
    return r;
}

template <int P, int SB>
__device__ __forceinline__ void stepf(
    int kk, int t, int t4, const float* __restrict__ Cb,
    int rb0, int rb1, int rb2, int rb3,
    float4& c0, float4& c1, float4& c2, float4& c3,
    float4& n0, float4& n1, float4& n2, float4& n3,
    float4& s00, float4& s01, float4& s02, float4& s03,
    float4& s10, float4& s11, float4& s12, float4& s13,
    float4& s20, float4& s21, float4& s22, float4& s23,
    float4& s30, float4& s31, float4& s32, float4& s33,
    float& w10, float& w11, float& w12, float& w13,
    float& w20, float& w21, float& w22, float& w23,
    float& pd1, float& pd2)
{
    const int colr = kk + (20 - P) - t4;
    const int col  = colr < 0 ? 0 : (colr > 252 ? 252 : colr);
    const int rb   = (P == 0) ? rb0 : (P == 1) ? rb1 : (P == 2) ? rb2 : rb3;
    const float4 ld = *(const float4*)(Cb + rb + col);   // unconditional

    float4& cP = (P == 0) ? c0 : (P == 1) ? c1 : (P == 2) ? c2 : c3;
    float4& nP = (P == 0) ? n0 : (P == 1) ? n1 : (P == 2) ? n2 : n3;
    float4& sP =
        (SB == 0) ? ((P == 0) ? s00 : (P == 1) ? s01 : (P == 2) ? s02 : s03)
      : (SB == 1) ? ((P == 0) ? s10 : (P == 1) ? s11 : (P == 2) ? s12 : s13)
      : (SB == 2) ? ((P == 0) ? s20 : (P == 1) ? s21 : (P == 2) ? s22 : s23)
                  : ((P == 0) ? s30 : (P == 1) ? s31 : (P == 2) ? s32 : s33);

    // convert the slot loaded 16 steps ago; zero it if it was past-the-end
    const bool junk = (colr > 268);
    float4 gq;
    gq.x = junk ? 0.0f : EXP2F(sP.x * -L2E);
    gq.y = junk ? 0.0f : EXP2F(sP.y * -L2E);
    gq.z = junk ? 0.0f : EXP2F(sP.z * -L2E);
    gq.w = junk ? 0.0f : EXP2F(sP.w * -L2E);
    cP = nP;
    nP = gq;
    sP = ld;

    const float g0 = comp<(P    ) & 3>(c0);
    const float g1 = comp<(P + 3) & 3>(c1);
    const float g2 = comp<(P + 2) & 3>(c2);
    const float g3 = comp<(P + 1) & 3>(c3);

    const float e0 = g0 * (w10 + pd1 + pd2);   // preds: (r-1,j)=pd1, (r,j-1)=w10, (r-1,j-1)=pd2
    const float e1 = g1 * (w11 + w10 + w20);
    const float e2 = g2 * (w12 + w11 + w21);
    const float e3 = g3 * (w13 + w12 + w22);

    w20 = w10; w21 = w11; w22 = w12; w23 = w13;
    w10 = e0;  w11 = e1;  w12 = e2;  w13 = e3;

    const float nx = __shfl_up(e3, 1);
    pd2 = pd1;
    pd1 = (t == 0) ? 0.0f : nx;
}

__global__ __launch_bounds__(64, 1) void dp_softmin_wave(const float* __restrict__ C,
                                                         float* __restrict__ out) {
    const int b = blockIdx.x;
    const int t = threadIdx.x;
    const float* Cb = C + ((size_t)b << 16);
    const int t4 = 4 * t;

    const int rb0 = (t4 + 0) << 8;
    const int rb1 = (t4 + 1) << 8;
    const int rb2 = (t4 + 2) << 8;
    const int rb3 = (t4 + 3) << 8;

    auto cl = [](int c) { return c < 0 ? 0 : (c > 252 ? 252 : c); };
    auto q  = [&](int rb, int col) { return *(const float4*)(Cb + rb + col); };

    // init = fixed point of the unconditional machine for kk <= 0.
    // slot[P][SB] = raw load of the most recent virtual step kv <= 0 with
    // kv&3==P, (kv>>2)&3==SB: kv = P+4*SB-16 (colr_v = 4*SB+4-t4), except
    // (P,SB)=(0,0) where kv=0 (colr_v = 20-t4).
    float4 c0 = g4f(q(rb0, 0)), c1 = g4f(q(rb1, 0)),
           c2 = g4f(q(rb2, 0)), c3 = g4f(q(rb3, 0));
    float4 n0 = g4f(q(rb0, cl(4 - t4)));
    float4 n1 = c1, n2 = c2, n3 = c3;

    float4 s00 = q(rb0, cl(20 - t4));
    float4 s01 = q(rb1, cl(4 - t4));
    float4 s02 = q(rb2, cl(4 - t4));
    float4 s03 = q(rb3, cl(4 - t4));
    float4 s10 = q(rb0, cl(8 - t4)),  s11 = q(rb1, cl(8 - t4));
    float4 s12 = q(rb2, cl(8 - t4)),  s13 = q(rb3, cl(8 - t4));
    float4 s20 = q(rb0, cl(12 - t4)), s21 = q(rb1, cl(12 - t4));
    float4 s22 = q(rb2, cl(12 - t4)), s23 = q(rb3, cl(12 - t4));
    float4 s30 = q(rb0, cl(16 - t4)), s31 = q(rb1, cl(16 - t4));
    float4 s32 = q(rb2, cl(16 - t4)), s33 = q(rb3, cl(16 - t4));

    float w10 = 0.0f, w11 = 0.0f, w12 = 0.0f, w13 = 0.0f;
    float w20 = 0.0f, w21 = 0.0f, w22 = 0.0f, w23 = 0.0f;
    float pd1 = 0.0f, pd2 = 0.0f;
    int sig = 0;

    if (t == 0) w10 = c0.x;                // seed: w(0,0) = g(0,0)

#define ARGS t, t4, Cb, rb0, rb1, rb2, rb3, c0,c1,c2,c3, n0,n1,n2,n3, \
             s00,s01,s02,s03, s10,s11,s12,s13, s20,s21,s22,s23, s30,s31,s32,s33, \
             w10,w11,w12,w13, w20,w21,w22,w23, pd1,pd2

    // prologue kk = 1..15
    stepf<1,0>(1, ARGS);  stepf<2,0>(2, ARGS);  stepf<3,0>(3, ARGS);
    stepf<0,1>(4, ARGS);  stepf<1,1>(5, ARGS);  stepf<2,1>(6, ARGS);  stepf<3,1>(7, ARGS);
    stepf<0,2>(8, ARGS);  stepf<1,2>(9, ARGS);  stepf<2,2>(10, ARGS); stepf<3,2>(11, ARGS);
    stepf<0,3>(12, ARGS); stepf<1,3>(13, ARGS); stepf<2,3>(14, ARGS); stepf<3,3>(15, ARGS);

#pragma clang loop unroll(disable)
    for (int kb = 16; kb <= 480; kb += 16) {
        if ((kb & 63) == 0) {
            // block-floating renorm: exact power-of-2, sigma -= e
            float M = fmaxf(fmaxf(fmaxf(w10, w11), fmaxf(w12, w13)),
                            fmaxf(fmaxf(w20, w21), fmaxf(w22, w23)));
            #pragma unroll
            for (int m = 1; m < 64; m <<= 1) M = fmaxf(M, __shfl_xor(M, m));
            int e = ((__float_as_int(M) >> 23) & 255) - 127;
            float f = __int_as_float((127 - e) << 23);
            w10 *= f; w11 *= f; w12 *= f; w13 *= f;
            w20 *= f; w21 *= f; w22 *= f; w23 *= f;
            pd1 *= f; pd2 *= f;
            sig -= e;
        }
        stepf<0,0>(kb + 0, ARGS);  stepf<1,0>(kb + 1, ARGS);
        stepf<2,0>(kb + 2, ARGS);  stepf<3,0>(kb + 3, ARGS);
        stepf<0,1>(kb + 4, ARGS);  stepf<1,1>(kb + 5, ARGS);
        stepf<2,1>(kb + 6, ARGS);  stepf<3,1>(kb + 7, ARGS);
        stepf<0,2>(kb + 8, ARGS);  stepf<1,2>(kb + 9, ARGS);
        stepf<2,2>(kb + 10, ARGS); stepf<3,2>(kb + 11, ARGS);
        stepf<0,3>(kb + 12, ARGS); stepf<1,3>(kb + 13, ARGS);
        stepf<2,3>(kb + 14, ARGS); stepf<3,3>(kb + 15, ARGS);
    }

    // epilogue kk = 496..510
    stepf<0,0>(496, ARGS); stepf<1,0>(497, ARGS); stepf<2,0>(498, ARGS); stepf<3,0>(499, ARGS);
    stepf<0,1>(500, ARGS); stepf<1,1>(501, ARGS); stepf<2,1>(502, ARGS); stepf<3,1>(503, ARGS);
    stepf<0,2>(504, ARGS); stepf<1,2>(505, ARGS); stepf<2,2>(506, ARGS); stepf<3,2>(507, ARGS);
    stepf<0,3>(508, ARGS); stepf<1,3>(509, ARGS); stepf<2,3>(510, ARGS);
#undef ARGS

    // corner cell (255,255): lane 63, E = sig - log2(w13), D = E * ln2
    if (t == 63) out[b] = ((float)sig - LOG2F(w13)) * LN2;
}

extern "C" void kernel_launch(void* const* d_in, const int* in_sizes, int n_in,
                              void* d_out, int out_size, void* d_ws, size_t ws_size,
                              hipStream_t stream) {
    const float* C = (const float*)d_in[0];
    float* out = (float*)d_out;
    dp_softmin_wave<<<512, 64, 0, stream>>>(C, out);
}